// Round 17
// baseline (86.649 us; speedup 1.0000x reference)
//
#include <hip/hip_runtime.h>
#include <hip/hip_bf16.h>

#define Dd   64
#define BWk  31
#define NTH  256
#define RS   64                 // result-tile row stride (floats)

typedef float  f32x4   __attribute__((ext_vector_type(4)));
typedef short  bf16x8  __attribute__((ext_vector_type(8)));
typedef float  float4a __attribute__((ext_vector_type(4), aligned(4)));

__device__ __forceinline__ unsigned pk2(float lo, float hi) {
    __hip_bfloat162 h = __float22bfloat162_rn(make_float2(lo, hi));
    union { __hip_bfloat162 h; unsigned u; } c; c.h = h; return c.u;
}

// barrier that only waits for LDS ops (NOT the global store / load queues).
__device__ __forceinline__ void lds_barrier() {
    asm volatile("s_waitcnt lgkmcnt(0)" ::: "memory");
    __builtin_amdgcn_s_barrier();
    __builtin_amdgcn_sched_barrier(0);
}

__global__ __launch_bounds__(NTH, 3)
void band_mfma(const float* __restrict__ pw,
               const float* __restrict__ x,
               float* __restrict__ out)
{
    // ONLY the double-buffered result tile in LDS now (A-frags go straight
    // from global to registers): 2 x 8192 B = 16384 B -> occupancy is
    // VGPR-capped at 4 blocks/CU (16 waves) instead of LDS-capped at 3.
    __shared__ float tile[2][32 * RS];

    const int tid = threadIdx.x;

    // --- XCD y-banding swizzle (validated R15/R16) ---
    const unsigned id   = blockIdx.x;        // 0..1023
    const unsigned xcd  = id & 7u;
    const unsigned slot = id >> 3;           // 0..127
    const int bx = (int)(slot & 3u);         // bx fastest (R16, neutral)
    const int y  = (int)(xcd * 32u + (slot >> 2));
    const int x0 = bx * 64;

    // exact scale-4 half-pixel y interpolation (validated rounds 1-16)
    const int yq = y >> 2, ry = y & 3;
    const int y0i = yq + ((ry < 2) ? -1 : 0);
    const float fy = 0.125f + 0.25f * (float)((ry + 2) & 3);
    const int y0c = (y0i < 0) ? 0 : y0i;
    const int y1c = (y0i + 1 > Dd - 1) ? Dd - 1 : (y0i + 1);
    const int cxb = (x0 >> 2) - 1;      // leftmost coarse col needed

    const int lane = tid & 63;
    const int px   = lane & 15;         // MFMA column = pixel-in-tile
    const int q    = lane >> 4;         // k-slice / C row group
    const int t    = tid >> 6;          // wave id = 16-px tile (0..3)
    const int xt0  = x0 + 16 * t;       // tile's global x base

    // ---- A-frags DIRECT from global with in-register y-interp ----
    // A[j][mh] = wY[col=cxb+4t+j][n=mh*16+px][k=8q..8q+7], k=31 padded 0.
    // q==3 uses overlapping loads at k=24 and k=27 so nothing reads past pw.
    const int offA = (q == 3) ? 24 : 8 * q;
    const int offB = (q == 3) ? 27 : 8 * q + 4;
    bf16x8 A[6][2];
    #pragma unroll
    for (int j = 0; j < 6; ++j) {
        int col = cxb + 4 * t + j;
        col = (col < 0) ? 0 : ((col > Dd - 1) ? Dd - 1 : col);
        #pragma unroll
        for (int mh = 0; mh < 2; ++mh) {
            const int n = mh * 16 + px;
            const size_t rbase = ((size_t)n * 4096 + (size_t)col) * BWk;
            const float* r0 = pw + rbase + (size_t)y0c * (Dd * BWk);
            const float* r1 = pw + rbase + (size_t)y1c * (Dd * BWk);
            float4a a0 = *(const float4a*)(r0 + offA);
            float4a a1 = *(const float4a*)(r0 + offB);
            float4a b0 = *(const float4a*)(r1 + offA);
            float4a b1 = *(const float4a*)(r1 + offB);
            const float v0 = fmaf(fy, b0.x - a0.x, a0.x);
            const float v1 = fmaf(fy, b0.y - a0.y, a0.y);
            const float v2 = fmaf(fy, b0.z - a0.z, a0.z);
            const float v3 = fmaf(fy, b0.w - a0.w, a0.w);
            float v4, v5, v6, v7;
            if (q == 3) {                       // a1/b1 cover k=27..30
                v4 = fmaf(fy, b1.y - a1.y, a1.y);   // k=28
                v5 = fmaf(fy, b1.z - a1.z, a1.z);   // k=29
                v6 = fmaf(fy, b1.w - a1.w, a1.w);   // k=30
                v7 = 0.f;                           // k=31 pad
            } else {                            // a1/b1 cover k=8q+4..8q+7
                v4 = fmaf(fy, b1.x - a1.x, a1.x);
                v5 = fmaf(fy, b1.y - a1.y, a1.y);
                v6 = fmaf(fy, b1.z - a1.z, a1.z);
                v7 = fmaf(fy, b1.w - a1.w, a1.w);
            }
            union { unsigned u[4]; bf16x8 v; } pa;
            pa.u[0] = pk2(v0, v1);
            pa.u[1] = pk2(v2, v3);
            pa.u[2] = pk2(v4, v5);
            pa.u[3] = pk2(v6, v7);
            A[j][mh] = pa.v;
        }
    }

    // per-pixel x-interp coefficients c_j (2 of 6 nonzero); (xt0+px)&3 == px&3
    const int rx = px & 3;
    const float fx = 0.125f + 0.25f * (float)((rx + 2) & 3);
    const int j0 = (px >> 2) + ((rx < 2) ? 0 : 1);   // 0..4
    float c[6];
    #pragma unroll
    for (int j = 0; j < 6; ++j)
        c[j] = (j == j0) ? (1.f - fx) : ((j == j0 + 1) ? fx : 0.f);

    const int gxb = xt0 + px + q * 8 - 15;           // B element i -> x[gxb + i]
    const bool edge = (bx == 0 && t == 0) || (bx == 3 && t == 3);
    const f32x4 zero = {0.f, 0.f, 0.f, 0.f};

    // store-phase lane roles: instr s covers rows 8t+4s+rr, 16B (4 px) per lane
    const int rr = lane >> 4;           // row within the 4-row group
    const int ii = lane & 15;           // 16B chunk within the 64-px row
    const size_t sb = (size_t)y * 256 + (size_t)x0 + (size_t)(ii * 4);

    #pragma unroll 2
    for (int bc = 0; bc < 32; ++bc) {
        const float* xrow = x + ((size_t)bc * 256 + y) * 256;

        // B-frag: Hankel column px, k-slice q (direct from global, L2-hot)
        float4a v0, v1;
        if (!edge) {
            v0 = *(const float4a*)(xrow + gxb);
            v1 = *(const float4a*)(xrow + gxb + 4);
        } else {
            float tv[8];
            #pragma unroll
            for (int i = 0; i < 8; ++i) {
                int gx = gxb + i;
                tv[i] = ((unsigned)gx < 256u) ? xrow[gx] : 0.f;
            }
            v0 = *(float4a*)&tv[0]; v1 = *(float4a*)&tv[4];
        }
        union { unsigned u[4]; bf16x8 v; } bb;
        bb.u[0] = pk2(v0.x, v0.y);
        bb.u[1] = pk2(v0.z, v0.w);
        bb.u[2] = pk2(v1.x, v1.y);
        bb.u[3] = pk2(v1.z, v1.w);
        const bf16x8 B = bb.v;

        float* tl = tile[bc & 1];
        #pragma unroll
        for (int mh = 0; mh < 2; ++mh) {
            f32x4 acc = zero;
            #pragma unroll
            for (int j = 0; j < 6; ++j) {
                f32x4 g = __builtin_amdgcn_mfma_f32_16x16x32_bf16(
                              A[j][mh], B, zero, 0, 0, 0);
                acc += g * c[j];               // x-interp blend, exact in f32
            }
            // C layout: col = px, row = 4q + reg -> n = mh*16 + 4q + reg
            float* w = tl + (mh * 16 + q * 4) * RS + 16 * t + px;
            w[0]      = acc.x;
            w[RS]     = acc.y;
            w[2 * RS] = acc.z;
            w[3 * RS] = acc.w;
        }
        lds_barrier();   // LDS visibility only; nt stores keep draining async

        // store phase: two dwordx4 wave-stores (rows 8t..8t+7 in 4-row groups)
        const float* ts = tile[bc & 1];
        #pragma unroll
        for (int s = 0; s < 2; ++s) {
            const int row = t * 8 + s * 4 + rr;          // n index (0..31)
            f32x4 v = *(const f32x4*)&ts[row * RS + ii * 4];
            f32x4* dst = (f32x4*)(out + (size_t)(bc * 32 + row) * 65536 + sb);
            __builtin_nontemporal_store(v, dst);
        }
    }
}

extern "C" void kernel_launch(void* const* d_in, const int* in_sizes, int n_in,
                              void* d_out, int out_size, void* d_ws, size_t ws_size,
                              hipStream_t stream) {
    const float* pw = (const float*)d_in[0];   // pre_weights [32,4096,31]
    const float* x  = (const float*)d_in[1];   // x [4,8,256,256] -> [32,256,256]
    float* out = (float*)d_out;                // [32,32,256,256] f32

    dim3 grid(1024, 1, 1);
    dim3 block(NTH, 1, 1);
    band_mfma<<<grid, block, 0, stream>>>(pw, x, out);
}

// Round 18
// 72.425 us; speedup vs baseline: 1.1964x; 1.1964x over previous
//
#include <hip/hip_runtime.h>
#include <hip/hip_bf16.h>

#define Dd   64
#define BWk  31
#define NTH  256
#define CS   256                // pass-buffer per-col stride (shorts): 8 n x 32 k
#define RS   64                 // result-tile row stride (floats)

typedef float  f32x4   __attribute__((ext_vector_type(4)));
typedef short  bf16x8  __attribute__((ext_vector_type(8)));
typedef float  float4a __attribute__((ext_vector_type(4), aligned(4)));

__device__ __forceinline__ unsigned pk2(float lo, float hi) {
    __hip_bfloat162 h = __float22bfloat162_rn(make_float2(lo, hi));
    union { __hip_bfloat162 h; unsigned u; } c; c.h = h; return c.u;
}

// barrier that only waits for LDS ops (NOT the global store / load queues).
__device__ __forceinline__ void lds_barrier() {
    asm volatile("s_waitcnt lgkmcnt(0)" ::: "memory");
    __builtin_amdgcn_s_barrier();
    __builtin_amdgcn_sched_barrier(0);
}

__global__ __launch_bounds__(NTH, 3)   // VGPR cap 85; occupancy becomes 4/CU via usage
void band_mfma(const float* __restrict__ pw,
               const float* __restrict__ x,
               float* __restrict__ out)
{
    // pass-shared y-interp weight buffer: [c=18][n_l=8][k=32 (k31=0)] bf16
    __shared__ unsigned short wYb[18 * CS];          // 9216 B
    // double-buffered result tile: [32 n][64 px], row stride 64
    __shared__ float tile[2][32 * RS];               // 16384 B (total 25600 B)

    const int tid = threadIdx.x;

    // --- XCD y-banding swizzle (validated R15) ---
    const unsigned id   = blockIdx.x;        // 0..1023
    const unsigned xcd  = id & 7u;
    const unsigned slot = id >> 3;           // 0..127
    const int bx = (int)(slot & 3u);
    const int y  = (int)(xcd * 32u + (slot >> 2));
    const int x0 = bx * 64;

    // exact scale-4 half-pixel y interpolation (validated rounds 1-17)
    const int yq = y >> 2, ry = y & 3;
    const int y0i = yq + ((ry < 2) ? -1 : 0);
    const float fy = 0.125f + 0.25f * (float)((ry + 2) & 3);
    const int y0c = (y0i < 0) ? 0 : y0i;
    const int y1c = (y0i + 1 > Dd - 1) ? Dd - 1 : (y0i + 1);
    const int cxb = (x0 >> 2) - 1;      // leftmost coarse col staged

    const int lane = tid & 63;
    const int px   = lane & 15;         // MFMA column = pixel-in-tile
    const int q    = lane >> 4;         // k-slice / C row group
    const int t    = tid >> 6;          // wave id = 16-px tile (0..3)
    const int xt0  = x0 + 16 * t;       // tile's global x base

    // ---- A-frags via 4 coalesced passes of 8 n through the small buffer ----
    // stage task: (n_l = tid>>5, c-group = (tid>>3)&3, k-quad = tid&7)
    bf16x8 A[6][2];
    {
        const int kq  = tid & 7;
        const int k0  = kq << 2;            // 0,4,...,28
        const int cg  = (tid >> 3) & 3;
        const int n_l = tid >> 5;           // 0..7
        const bool lastk = (kq == 7);
        #pragma unroll
        for (int p = 0; p < 4; ++p) {
            const int n_g = p * 8 + n_l;
            const size_t rb0 = ((size_t)n_g * 4096) * BWk + k0;
            #pragma unroll
            for (int ci = cg; ci < 18; ci += 4) {
                int cx = cxb + ci;
                cx = (cx < 0) ? 0 : ((cx > Dd - 1) ? Dd - 1 : cx);
                const size_t rb = rb0 + (size_t)cx * BWk;
                float4a a = *(const float4a*)(pw + rb + (size_t)y0c * (Dd * BWk));
                float4a b = *(const float4a*)(pw + rb + (size_t)y1c * (Dd * BWk));
                float v0 = fmaf(fy, b.x - a.x, a.x);
                float v1 = fmaf(fy, b.y - a.y, a.y);
                float v2 = fmaf(fy, b.z - a.z, a.z);
                float v3 = lastk ? 0.f : fmaf(fy, b.w - a.w, a.w);   // k=31 pad
                *(uint2*)&wYb[ci * CS + n_l * 32 + k0] =
                    make_uint2(pk2(v0, v1), pk2(v2, v3));
            }
            __syncthreads();
            // frag rows n = mh*16 + px live in pass p = 2*mh + (px>>3)
            if ((px >> 3) == (p & 1)) {
                const int mh = p >> 1;
                #pragma unroll
                for (int j = 0; j < 6; ++j)
                    A[j][mh] = *(const bf16x8*)
                        &wYb[(4 * t + j) * CS + (px & 7) * 32 + q * 8];
            }
            __syncthreads();
        }
    }

    // per-pixel x-interp coefficients c_j (2 of 6 nonzero); (xt0+px)&3 == px&3
    const int rx = px & 3;
    const float fx = 0.125f + 0.25f * (float)((rx + 2) & 3);
    const int j0 = (px >> 2) + ((rx < 2) ? 0 : 1);   // 0..4
    float c[6];
    #pragma unroll
    for (int j = 0; j < 6; ++j)
        c[j] = (j == j0) ? (1.f - fx) : ((j == j0 + 1) ? fx : 0.f);

    const int gxb = xt0 + px + q * 8 - 15;           // B element i -> x[gxb + i]
    const bool edge = (bx == 0 && t == 0) || (bx == 3 && t == 3);
    const f32x4 zero = {0.f, 0.f, 0.f, 0.f};

    // store-phase lane roles: instr s covers rows 8t+4s+rr, 16B (4 px) per lane
    const int rr = lane >> 4;           // row within the 4-row group
    const int ii = lane & 15;           // 16B chunk within the 64-px row
    const size_t sb = (size_t)y * 256 + (size_t)x0 + (size_t)(ii * 4);

    #pragma unroll 2
    for (int bc = 0; bc < 32; ++bc) {
        const float* xrow = x + ((size_t)bc * 256 + y) * 256;

        // B-frag: Hankel column px, k-slice q (direct from global, L2-hot)
        float4a v0, v1;
        if (!edge) {
            v0 = *(const float4a*)(xrow + gxb);
            v1 = *(const float4a*)(xrow + gxb + 4);
        } else {
            float tv[8];
            #pragma unroll
            for (int i = 0; i < 8; ++i) {
                int gx = gxb + i;
                tv[i] = ((unsigned)gx < 256u) ? xrow[gx] : 0.f;
            }
            v0 = *(float4a*)&tv[0]; v1 = *(float4a*)&tv[4];
        }
        union { unsigned u[4]; bf16x8 v; } bb;
        bb.u[0] = pk2(v0.x, v0.y);
        bb.u[1] = pk2(v0.z, v0.w);
        bb.u[2] = pk2(v1.x, v1.y);
        bb.u[3] = pk2(v1.z, v1.w);
        const bf16x8 B = bb.v;

        float* tl = tile[bc & 1];
        #pragma unroll
        for (int mh = 0; mh < 2; ++mh) {
            f32x4 acc = zero;
            #pragma unroll
            for (int j = 0; j < 6; ++j) {
                f32x4 g = __builtin_amdgcn_mfma_f32_16x16x32_bf16(
                              A[j][mh], B, zero, 0, 0, 0);
                acc += g * c[j];               // x-interp blend, exact in f32
            }
            // C layout: col = px, row = 4q + reg -> n = mh*16 + 4q + reg
            float* w = tl + (mh * 16 + q * 4) * RS + 16 * t + px;
            w[0]      = acc.x;
            w[RS]     = acc.y;
            w[2 * RS] = acc.z;
            w[3 * RS] = acc.w;
        }
        lds_barrier();   // LDS visibility only; nt stores keep draining async

        // store phase: two dwordx4 wave-stores (rows 8t..8t+7 in 4-row groups)
        const float* ts = tile[bc & 1];
        #pragma unroll
        for (int s = 0; s < 2; ++s) {
            const int row = t * 8 + s * 4 + rr;          // n index (0..31)
            f32x4 v = *(const f32x4*)&ts[row * RS + ii * 4];
            f32x4* dst = (f32x4*)(out + (size_t)(bc * 32 + row) * 65536 + sb);
            __builtin_nontemporal_store(v, dst);
        }
    }
}

extern "C" void kernel_launch(void* const* d_in, const int* in_sizes, int n_in,
                              void* d_out, int out_size, void* d_ws, size_t ws_size,
                              hipStream_t stream) {
    const float* pw = (const float*)d_in[0];   // pre_weights [32,4096,31]
    const float* x  = (const float*)d_in[1];   // x [4,8,256,256] -> [32,256,256]
    float* out = (float*)d_out;                // [32,32,256,256] f32

    dim3 grid(1024, 1, 1);
    dim3 block(NTH, 1, 1);
    band_mfma<<<grid, block, 0, stream>>>(pw, x, out);
}